// Round 3
// baseline (230.804 us; speedup 1.0000x reference)
//
#include <hip/hip_runtime.h>
#include <math.h>

// Sobel gradient magnitude, zero-padded 3x3 cross stencil.
// x: [8, 64, 256, 256] f32 -> out same shape.
// gv = x[i+1,j] - x[i-1,j]; gh = x[i,j+1] - x[i,j-1]; out = sqrt(gv^2+gh^2+eps)
//
// ONE WAVE == ONE ROW (W=256 = 64 lanes x float4). Horizontal halo via
// __shfl (lane 0/63 edge == zero-pad edge, no loads, no divergence).
// R=8 rows per wave: 10 row-loads -> 8 rows out (1.25x read amp), 10
// independent dwordx4 loads in flight for latency hiding.
// Output stores are nontemporal (never re-read; keep L2 for input halos).

#define PLANE_H 256
#define PLANE_W 256
#define R 8   // rows per wave

typedef float v4 __attribute__((ext_vector_type(4)));

__global__ __launch_bounds__(256) void sobel_kernel(const float* __restrict__ x,
                                                    float* __restrict__ out) {
    const int tid  = threadIdx.x;
    const int lane = tid & 63;
    const int w    = blockIdx.x * 4 + (tid >> 6);    // global wave id
    const int plane = w >> 5;                        // 32 wave-groups per plane
    const int r0    = (w & 31) << 3;                 // first of 8 rows

    const size_t base = ((size_t)plane << 16) + ((size_t)r0 << 8) + ((size_t)lane << 2);
    const float* p = x + base;

    // 10-row register window: rows r0-1 .. r0+8 (zero outside plane).
    v4 win[R + 2];
    win[0] = (r0 > 0) ? *(const v4*)(p - PLANE_W) : (v4)(0.f);
#pragma unroll
    for (int i = 0; i < R; ++i)
        win[i + 1] = *(const v4*)(p + (i << 8));
    win[R + 1] = (r0 + R < PLANE_H) ? *(const v4*)(p + (R << 8)) : (v4)(0.f);

    float* po = out + base;
    const float eps = 1e-6f;

#pragma unroll
    for (int i = 0; i < R; ++i) {
        v4 c  = win[i + 1];
        v4 up = win[i];
        v4 dn = win[i + 2];

        // horizontal halo from neighbor lanes; wave edge == plane edge -> 0
        float left  = __shfl_up(c.w, 1, 64);
        float right = __shfl_down(c.x, 1, 64);
        if (lane == 0)  left  = 0.f;
        if (lane == 63) right = 0.f;

        float gh0 = c.y   - left;
        float gh1 = c.z   - c.x;
        float gh2 = c.w   - c.y;
        float gh3 = right - c.z;

        float gv0 = dn.x - up.x;
        float gv1 = dn.y - up.y;
        float gv2 = dn.z - up.z;
        float gv3 = dn.w - up.w;

        v4 o;
        o.x = sqrtf(gv0 * gv0 + gh0 * gh0 + eps);
        o.y = sqrtf(gv1 * gv1 + gh1 * gh1 + eps);
        o.z = sqrtf(gv2 * gv2 + gh2 * gh2 + eps);
        o.w = sqrtf(gv3 * gv3 + gh3 * gh3 + eps);

        __builtin_nontemporal_store(o, (v4*)(po + (i << 8)));
    }
}

extern "C" void kernel_launch(void* const* d_in, const int* in_sizes, int n_in,
                              void* d_out, int out_size, void* d_ws, size_t ws_size,
                              hipStream_t stream) {
    const float* x = (const float*)d_in[0];
    float* out = (float*)d_out;
    // 8*64 = 512 planes; 32 waves/plane (8 rows each); 4 waves/block
    int planes = out_size / (PLANE_H * PLANE_W);         // 512
    int totalWaves = planes * (PLANE_H / R);             // 16384
    int block = 256;
    int grid = totalWaves / 4;                           // 4096
    sobel_kernel<<<grid, block, 0, stream>>>(x, out);
}

// Round 4
// 221.188 us; speedup vs baseline: 1.0435x; 1.0435x over previous
//
#include <hip/hip_runtime.h>
#include <math.h>

// Sobel gradient magnitude, zero-padded 3x3 cross stencil.
// x: [8, 64, 256, 256] f32 -> out same shape.
// gv = x[i+1,j] - x[i-1,j]; gh = x[i,j+1] - x[i,j-1]; out = sqrt(gv^2+gh^2+eps)
//
// ONE WAVE == ONE ROW (W=256 = 64 lanes x float4). Horizontal halo via
// __shfl (lane 0/63 edge == zero-pad edge, no loads, no divergence).
// R=4 rows/wave: 6 row-loads -> 4 rows out. 32768 waves / 8192 blocks ->
// 4 rounds/CU for smooth ramp. Normal stores (NT regressed: fills hit
// 6.7 TB/s with normal stores; NT kernel pinned at 2.6 TB/s).
// XCD swizzle: all 16 blocks of a plane -> same XCD (blockIdx%8 == plane%8),
// so halo rows shared between adjacent blocks hit the local 4 MiB L2.

#define PLANE_H 256
#define PLANE_W 256
#define R 4   // rows per wave

typedef float v4 __attribute__((ext_vector_type(4)));

__global__ __launch_bounds__(256) void sobel_kernel(const float* __restrict__ x,
                                                    float* __restrict__ out) {
    const int tid  = threadIdx.x;
    const int lane = tid & 63;

    // XCD-affinity remap: consecutive blockIdx round-robin across 8 XCDs.
    // Make plane p's 16 blocks all satisfy blockIdx%8 == p%8 and be
    // consecutive in dispatch order on that XCD.
    const int b    = blockIdx.x;          // 0..8191
    const int xcd  = b & 7;
    const int slot = b >> 3;              // 0..1023 (per-XCD dispatch order)
    const int plane = ((slot >> 4) << 3) + xcd;   // 0..511, plane%8==xcd
    const int seg   = slot & 15;                  // 16-row segment in plane
    const int r0    = (seg << 4) + ((tid >> 6) << 2);  // wave's first row

    const size_t base = ((size_t)plane << 16) + ((size_t)r0 << 8) + ((size_t)lane << 2);
    const float* p = x + base;

    // 6-row register window: rows r0-1 .. r0+4 (zero outside plane).
    v4 win[R + 2];
    win[0] = (r0 > 0) ? *(const v4*)(p - PLANE_W) : (v4)(0.f);
#pragma unroll
    for (int i = 0; i < R; ++i)
        win[i + 1] = *(const v4*)(p + (i << 8));
    win[R + 1] = (r0 + R < PLANE_H) ? *(const v4*)(p + (R << 8)) : (v4)(0.f);

    float* po = out + base;
    const float eps = 1e-6f;

#pragma unroll
    for (int i = 0; i < R; ++i) {
        v4 c  = win[i + 1];
        v4 up = win[i];
        v4 dn = win[i + 2];

        // horizontal halo from neighbor lanes; wave edge == plane edge -> 0
        float left  = __shfl_up(c.w, 1, 64);
        float right = __shfl_down(c.x, 1, 64);
        if (lane == 0)  left  = 0.f;
        if (lane == 63) right = 0.f;

        float gh0 = c.y   - left;
        float gh1 = c.z   - c.x;
        float gh2 = c.w   - c.y;
        float gh3 = right - c.z;

        float gv0 = dn.x - up.x;
        float gv1 = dn.y - up.y;
        float gv2 = dn.z - up.z;
        float gv3 = dn.w - up.w;

        v4 o;
        o.x = sqrtf(gv0 * gv0 + gh0 * gh0 + eps);
        o.y = sqrtf(gv1 * gv1 + gh1 * gh1 + eps);
        o.z = sqrtf(gv2 * gv2 + gh2 * gh2 + eps);
        o.w = sqrtf(gv3 * gv3 + gh3 * gh3 + eps);

        *(v4*)(po + (i << 8)) = o;
    }
}

extern "C" void kernel_launch(void* const* d_in, const int* in_sizes, int n_in,
                              void* d_out, int out_size, void* d_ws, size_t ws_size,
                              hipStream_t stream) {
    const float* x = (const float*)d_in[0];
    float* out = (float*)d_out;
    // 512 planes x 16 blocks/plane (4 waves x 4 rows = 16 rows/block)
    int planes = out_size / (PLANE_H * PLANE_W);     // 512
    int grid = planes * 16;                          // 8192
    int block = 256;
    sobel_kernel<<<grid, block, 0, stream>>>(x, out);
}